// Round 6
// baseline (240.333 us; speedup 1.0000x reference)
//
#include <hip/hip_runtime.h>
#include <hip/hip_fp16.h>
#include <math.h>

// Problem constants
#define NCH 72            // total channels (8*1 + 8*3 + 8*5)
#define SP  32768         // 32^3 spatial
#define NBATCH 8
#define NTOT (NBATCH*SP)  // per-channel element count = 262144

// ws layout (float offsets for the small stuff)
#define WS_SUMX   0       // 72
#define WS_SUMSQ  72      // 72
#define WS_SCALE  144     // 72 (unused now; kept for layout stability)
#define WS_BIAS   216     // 72
#define WS_K      288     // fp16 kernel matrix, fragment-blocked: 315 blocks * 1024 B

// byte offsets / strides for the packed fp16 x tensor
// chunk-major row layout: [cc(10)][x-slot(34)][16B]; cc 0..8 = ci chunks of 8,
// cc 9 = zero chunk (k-pad). Row is 5440 B = 2720 ushorts.
#define WS_XH_BYTES 323712          // 288*4 + 322560, 16B aligned
#define XH_ROW   2720               // ushorts per row (10 cc * 34 slots * 8)
#define XH_PLANE 87040              // 32 * XH_ROW
#define XH_BATCH 2785280            // 32 * XH_PLANE

typedef __attribute__((ext_vector_type(8))) _Float16 half8;
typedef __attribute__((ext_vector_type(4))) float float4v;
typedef __attribute__((ext_vector_type(4))) int int4v;

__device__ __forceinline__ void chmap(int c, int& f, int& m, int& d, int& dim) {
  if (c < 8)       { f = 0; m = c;          d = 0;          dim = 1; }
  else if (c < 32) { f = 1; m = (c - 8)/3;  d = (c - 8)%3;  dim = 3; }
  else             { f = 2; m = (c - 32)/5; d = (c - 32)%5; dim = 5; }
}

// ---------------- prepack: x -> fp16 chunk-major rows + fused BN stats ----------
// grid (64, 8): blockIdx.x = z*2 + half; block = half a z-plane (2 chunks of 256 pos)
__global__ __launch_bounds__(256) void prepack_kernel(const float* __restrict__ x,
                                                      float* __restrict__ ws) {
  __shared__ __align__(16) short tile[256 * 88];   // [pos(256)][ci(88 pad)] = 45 KB
  __shared__ float segS[72][3], segQ[72][3];
  const int t    = threadIdx.x;
  const int z    = blockIdx.x >> 1;
  const int half = blockIdx.x & 1;
  const int b    = blockIdx.y;
  ushort* xh = (ushort*)((char*)ws + WS_XH_BYTES);
  const float* xb = x + (size_t)b * NCH * SP + z * 1024 + half * 512;

  const int ci_s = t % 72, seg = t / 72;   // stats mapping (t < 216)
  float accS = 0.f, accQ = 0.f;

  for (int c = 0; c < 2; ++c) {
    if (c) __syncthreads();                 // protect tile reuse
    // phase 1: coalesced fp32 loads (fully unrolled), short4 LDS writes
    #pragma unroll
    for (int cig = 0; cig < 18; ++cig) {
      float v0 = xb[(size_t)(cig*4 + 0) * SP + c * 256 + t];
      float v1 = xb[(size_t)(cig*4 + 1) * SP + c * 256 + t];
      float v2 = xb[(size_t)(cig*4 + 2) * SP + c * 256 + t];
      float v3 = xb[(size_t)(cig*4 + 3) * SP + c * 256 + t];
      short s4[4] = { (short)__half_as_short(__float2half(v0)),
                      (short)__half_as_short(__float2half(v1)),
                      (short)__half_as_short(__float2half(v2)),
                      (short)__half_as_short(__float2half(v3)) };
      *(int2*)&tile[t * 88 + cig * 4] = *(const int2*)s4;   // 8B aligned
    }
    __syncthreads();
    // phase 2a: chunk-major writeout. Per cc (0..8): thread t writes its position's
    // 16B chunk to row (t>>5), slot (t&31): addr = row*2720 + cc*272 + slot*8 ushorts.
    {
      ushort* gb = xh + (size_t)b * XH_BATCH + (size_t)(z * 32 + (half * 2 + c) * 8) * XH_ROW;
      #pragma unroll
      for (int j = 0; j < 9; ++j) {
        const int4v v = *(const int4v*)&tile[t * 88 + j * 8];
        *(int4v*)(gb + (size_t)(t >> 5) * XH_ROW + j * 272 + (t & 31) * 8) = v;
      }
      // zero chunk (cc=9): 8 rows x 34 slots = 272 chunks of 16B
      {
        const int4v zz = (int4v){0, 0, 0, 0};
        int idx = t;
        *(int4v*)(gb + (size_t)(idx / 34) * XH_ROW + 9 * 272 + (idx % 34) * 8) = zz;
        idx = 256 + t;
        if (idx < 272)
          *(int4v*)(gb + (size_t)(idx / 34) * XH_ROW + 9 * 272 + (idx % 34) * 8) = zz;
      }
    }
    // phase 2b: stats from the tile (per-ci column sums); unrolled for ds overlap
    if (seg < 3) {
      const int p0 = seg * 86;
      const int pn = (seg == 2) ? 84 : 86;
      #pragma unroll 4
      for (int i = 0; i < pn; ++i) {
        const float v = __half2float(__short_as_half(tile[(p0 + i) * 88 + ci_s]));
        accS += v; accQ += v * v;
      }
    }
  }
  if (seg < 3) { segS[ci_s][seg] = accS; segQ[ci_s][seg] = accQ; }
  __syncthreads();
  if (t < 144) {
    const int which = t / 72, ci = t % 72;
    const float v = which ? (segQ[ci][0] + segQ[ci][1] + segQ[ci][2])
                          : (segS[ci][0] + segS[ci][1] + segS[ci][2]);
    atomicAdd(&ws[(which ? WS_SUMSQ : WS_SUMX) + ci], v);
  }
}

// ---------------- build fp16 kernel matrix + (block 0) bias; scales computed inline ----
__global__ __launch_bounds__(256) void build_half_kernel(const float* __restrict__ weight,
    float* __restrict__ ws,
    const float* __restrict__ b00, const float* __restrict__ b01, const float* __restrict__ b02,
    const float* __restrict__ b10, const float* __restrict__ b11, const float* __restrict__ b12,
    const float* __restrict__ b20, const float* __restrict__ b21, const float* __restrict__ b22) {
  const int tid = blockIdx.x * 256 + threadIdx.x;
  const float invN = 1.0f / (float)NTOT;
  if (tid < 315 * 512) {
    const int blk = tid >> 9;
    const int e   = tid & 511;
    const int tap = blk / 35;
    const int r   = blk - tap * 35;
    const int kc  = r / 5, cj = r - (r / 5) * 5;
    const int l   = e >> 3, j = e & 7;
    const int co  = cj * 16 + (l & 15);
    const int kk  = kc * 32 + ((l >> 4) << 3) + j;
    short val = 0;
    if (co < NCH && kk < 216) {
      const int dx = kk / 72, ci = kk - dx * 72;
      int fi, u, dd, di; chmap(co, fi, u, dd, di);
      int fj, v, ee, dj; chmap(ci, fj, v, ee, dj);
      // chained selects (no runtime-indexed pointer array -> no scratch)
      const int s9 = fi * 3 + fj;
      const float* basis = b00;
      if (s9 == 1) basis = b01;
      if (s9 == 2) basis = b02;
      if (s9 == 3) basis = b10;
      if (s9 == 4) basis = b11;
      if (s9 == 5) basis = b12;
      if (s9 == 6) basis = b20;
      if (s9 == 7) basis = b21;
      if (s9 == 8) basis = b22;
      // inverse-std for input channel ci, computed from raw sums
      float norm;
      if (ci < 8) {
        float m = ws[WS_SUMX + ci] * invN;
        norm = ws[WS_SUMSQ + ci] * invN - m * m;
      } else if (ci < 32) {
        int m0 = 8 + ((ci - 8) / 3) * 3;
        norm = (ws[WS_SUMSQ+m0] + ws[WS_SUMSQ+m0+1] + ws[WS_SUMSQ+m0+2]) * invN;
      } else {
        int m0 = 32 + ((ci - 32) / 5) * 5;
        norm = (ws[WS_SUMSQ+m0] + ws[WS_SUMSQ+m0+1] + ws[WS_SUMSQ+m0+2]
              + ws[WS_SUMSQ+m0+3] + ws[WS_SUMSQ+m0+4]) * invN;
      }
      const float sc = 1.0f / sqrtf(norm + 1e-5f);
      const float* wp = weight + s9 * 128 + (u * 8 + v) * 2;
      const float w0 = wp[0] * sc, w1 = wp[1] * sc;
      const int t = tap * 3 + dx;
      const float f = w0 * basis[(dd * dj + ee) * 27 + t]
                    + w1 * basis[((di + dd) * dj + ee) * 27 + t];
      val = __half_as_short(__float2half(f));
    }
    ((short*)(ws + WS_K))[tid] = val;
  }
  // block 0: compute compensating bias (72 floats; nonzero only for scalar outputs)
  if (blockIdx.x == 0) {
    __shared__ float s_mean[8], s_scale[8];
    const int c = threadIdx.x;
    if (c < 8) {
      float m = ws[WS_SUMX + c] * invN;
      float norm = ws[WS_SUMSQ + c] * invN - m * m;
      s_mean[c]  = m;
      s_scale[c] = 1.0f / sqrtf(norm + 1e-5f);
    }
    __syncthreads();
    if (c < NCH) {
      float bia = 0.f;
      if (c < 8) {
        float id0 = 0.f, id1 = 0.f;
        #pragma unroll
        for (int t = 0; t < 27; ++t) { id0 += b00[t]; id1 += b00[27 + t]; }
        #pragma unroll
        for (int v = 0; v < 8; ++v) {
          float s  = s_scale[v];
          float w0 = weight[(c*8 + v)*2 + 0] * s;
          float w1 = weight[(c*8 + v)*2 + 1] * s;
          bia -= (w0 * id0 + w1 * id1) * s_mean[v];
        }
      }
      ws[WS_BIAS + c] = bia;
    }
  }
}

// ---------------- conv: occupancy-driven 1z waves, single-buffer B in LDS ------
// 1920 blocks x 256 threads (4 y rows/block, 1 z-row per wave; y 30,31 clamped).
// XCD r = blk%8 = batch. Single 35.8KB Bsm -> 4 blocks/CU (LDS 143KB) and
// __launch_bounds__(256,4) caps VGPR at 128 -> 16 waves/CU: 3x the round-5
// concurrency, so per-wave stalls (85% of wave life at occ 1.34/SIMD) overlap.
// Per tap: barrier; STAGE(9 gll); A(kc0,kc1); vmcnt(4) (A stays in flight);
// barrier; 7 kc-groups with B-reg prefetch one ahead + A prefetch two ahead.
__global__ __launch_bounds__(256, 4) void conv_direct(const float* __restrict__ ws,
                                                      float* __restrict__ out) {
  extern __shared__ __align__(16) char Bsm[];   // 35840 B (one tap's B)

  const int lane = threadIdx.x & 63;
  const int wv   = threadIdx.x >> 6;   // 0..3: y sub-row
  const int lx   = lane & 15;
  const int q    = lane >> 4;
  const int i  = blockIdx.x;
  const int b  = i & 7;                // XCD-pinned batch
  const int q2 = i >> 3;               // 0..239
  const int yt = q2 & 7;               // 8 y-tiles of 4
  const int zp = q2 >> 3;              // 0..29 (output z-row)
  const int y  = yt * 4 + wv;          // 0..31 (30,31 are clamp-duplicates)
  const int yc = (y > 29) ? 29 : y;    // clamped row for loads (keeps reads in-bounds)

  const char* xhb = (const char*)ws + WS_XH_BYTES + (size_t)b * (XH_BATCH * 2);
  const char* Kb  = (const char*)(ws + WS_K);
  const float* __restrict__ bias = ws + WS_BIAS;

  const int lb16 = lane * 16;          // B-fragment: contiguous 1KB block + lane*16

  // per-kc A byte offset within a row (chunk-major): lanes of a q-group contiguous
  int aoffb[7];
  #pragma unroll
  for (int kc = 0; kc < 7; ++kc) {
    const int g = kc * 4 + q;
    aoffb[kc] = ((g >= 27) ? 9 * 544 : (g % 9) * 544 + (g / 9) * 16) + lx * 16;
  }

  float4v acc[2][5];
  #pragma unroll
  for (int s = 0; s < 2; ++s)
    #pragma unroll
    for (int cj = 0; cj < 5; ++cj)
      acc[s][cj] = (float4v){0.f, 0.f, 0.f, 0.f};

  // stage one tap's 35840 B: 2240 x 16B chunks, thread t -> t + k*256 (k=8 tail
  // mask is wave-uniform: waves 0-2 true, wave 3 false).
#define STAGE(TAP) {                                                              \
    const char* src_ = Kb + (size_t)(TAP) * 35840;                                \
    _Pragma("unroll")                                                             \
    for (int k = 0; k < 9; ++k) {                                                 \
      const int idx = (int)threadIdx.x + (k << 8);                                \
      if (idx < 2240) {                                                           \
        __builtin_amdgcn_global_load_lds(                                         \
          (const __attribute__((address_space(1))) void*)(src_ + (size_t)idx*16), \
          (__attribute__((address_space(3))) void*)(Bsm + ((k<<8) + (wv<<6))*16), \
          16, 0, 0);                                                              \
      }                                                                           \
    }                                                                             \
  }

#define LOADA(R0, KC, A) {                                                        \
    const int ao_ = aoffb[KC];                                                    \
    A[0] = *(const half8*)((R0) + ao_);                                           \
    A[1] = *(const half8*)((R0) + ao_ + 256);                                     \
  }

#define BPRE(KC, BQ) {                                                            \
    BQ[0] = *(const half8*)(Bsm + ((KC)*5 + 0)*1024 + lb16);                      \
    BQ[1] = *(const half8*)(Bsm + ((KC)*5 + 1)*1024 + lb16);                      \
    BQ[2] = *(const half8*)(Bsm + ((KC)*5 + 2)*1024 + lb16);                      \
    BQ[3] = *(const half8*)(Bsm + ((KC)*5 + 3)*1024 + lb16);                      \
    BQ[4] = *(const half8*)(Bsm + ((KC)*5 + 4)*1024 + lb16);                      \
  }

#define MFQ(A, BF, CJ)                                                                      \
    acc[0][CJ] = __builtin_amdgcn_mfma_f32_16x16x32_f16(A[0], BF, acc[0][CJ], 0,0,0);       \
    acc[1][CJ] = __builtin_amdgcn_mfma_f32_16x16x32_f16(A[1], BF, acc[1][CJ], 0,0,0);

#define MFMAG(A, BQ) {                                                            \
    __builtin_amdgcn_s_setprio(1);                                                \
    MFQ(A, BQ[0], 0) MFQ(A, BQ[1], 1) MFQ(A, BQ[2], 2) MFQ(A, BQ[3], 3) MFQ(A, BQ[4], 4) \
    __builtin_amdgcn_s_setprio(0);                                                \
  }

  half8 AA[2], AB[2], AC[2], Bq0[5], Bq1[5];

  #pragma unroll 1
  for (int tap = 0; tap < 9; ++tap) {
    const int dz_ = tap / 3, dy_ = tap - 3 * dz_;
    const char* r0T = xhb + (size_t)(((zp + dz_) * 32) + (yc + dy_)) * (XH_ROW * 2);

    if (tap) __builtin_amdgcn_s_barrier();   // all waves done reading previous B
    STAGE(tap);                              // 9 gll (oldest in vmcnt)
    LOADA(r0T, 0, AA);                       // 2 loads (younger)
    LOADA(r0T, 1, AB);                       // 2 loads (youngest)
    asm volatile("s_waitcnt vmcnt(4)" ::: "memory");   // staging done; A in flight
    __builtin_amdgcn_s_barrier();            // staged B visible to all waves

    BPRE(0, Bq0);
    BPRE(1, Bq1); LOADA(r0T, 2, AC); MFMAG(AA, Bq0);
    BPRE(2, Bq0); LOADA(r0T, 3, AA); MFMAG(AB, Bq1);
    BPRE(3, Bq1); LOADA(r0T, 4, AB); MFMAG(AC, Bq0);
    BPRE(4, Bq0); LOADA(r0T, 5, AC); MFMAG(AA, Bq1);
    BPRE(5, Bq1); LOADA(r0T, 6, AA); MFMAG(AB, Bq0);
    BPRE(6, Bq0);                    MFMAG(AC, Bq1);
                                     MFMAG(AA, Bq0);
  }

#undef STAGE
#undef LOADA
#undef BPRE
#undef MFQ
#undef MFMAG

  // epilogue: D layout col(co)=lane&15, row(m=x)=q*4+reg; y>=30 waves are clamp-dupes
  if (y < 30) {
    #pragma unroll
    for (int cj = 0; cj < 5; ++cj) {
      const int co = cj * 16 + lx;
      if (co < NCH) {
        const float bv = bias[co];
        float* ob = out + ((size_t)(b * NCH + co) * 30 + zp) * 900 + y * 30;
        #pragma unroll
        for (int s = 0; s < 2; ++s) {
          const int x0 = s * 16 + q * 4;
          const float4v v = acc[s][cj];
          float2 p0; p0.x = v[0] + bv; p0.y = v[1] + bv;
          *(float2*)(ob + x0) = p0;
          if (x0 + 2 < 30) {
            float2 p1; p1.x = v[2] + bv; p1.y = v[3] + bv;
            *(float2*)(ob + x0 + 2) = p1;
          }
        }
      }
    }
  }
}

extern "C" void kernel_launch(void* const* d_in, const int* in_sizes, int n_in,
                              void* d_out, int out_size, void* d_ws, size_t ws_size,
                              hipStream_t stream) {
  const float* x = (const float*)d_in[0];
  const float* w = (const float*)d_in[1];
  const float* bs[9];
  for (int i = 0; i < 9; ++i) bs[i] = (const float*)d_in[2 + i];
  float* ws  = (float*)d_ws;
  float* out = (float*)d_out;

  hipMemsetAsync(d_ws, 0, 144 * sizeof(float), stream);   // stats accumulators

  prepack_kernel<<<dim3(64, NBATCH), 256, 0, stream>>>(x, ws);
  build_half_kernel<<<(315 * 512 + 255) / 256, 256, 0, stream>>>(
      w, ws, bs[0], bs[1], bs[2], bs[3], bs[4], bs[5], bs[6], bs[7], bs[8]);
  conv_direct<<<dim3(1920), 256, 35840, stream>>>(ws, out);
}